// Round 1
// baseline (598.695 us; speedup 1.0000x reference)
//
#include <hip/hip_runtime.h>
#include <hip/hip_bf16.h>
#include <math.h>

typedef __attribute__((ext_vector_type(8))) short bf16x8;
typedef __attribute__((ext_vector_type(4))) short short4v;
typedef __attribute__((ext_vector_type(4))) float f32x4;

#define MFMA16(a,b,c) __builtin_amdgcn_mfma_f32_16x16x32_bf16(a,b,c,0,0,0)

__device__ __forceinline__ unsigned short f2bf(float f) {
  union { float f; unsigned u; } v; v.f = f;
  unsigned r = v.u + 0x7FFFu + ((v.u >> 16) & 1u);
  return (unsigned short)(r >> 16);
}

__device__ __forceinline__ void async_load16(const void* g, void* lds) {
  __builtin_amdgcn_global_load_lds(
      (const __attribute__((address_space(1))) unsigned int*)g,
      (__attribute__((address_space(3))) unsigned int*)lds, 16, 0, 0);
}

// ---------------- RoPE table (fp64 for accuracy, one-shot) ----------------
__global__ void rope_table_kernel(float* __restrict__ tc, float* __restrict__ ts) {
  int i = blockIdx.x * 256 + threadIdx.x;
  if (i >= 2048 * 32) return;
  int s = i >> 5, j = i & 31;
  double invf = pow(10000.0, -(double)(2 * j) / 64.0);
  double ang = (double)s * invf;
  tc[i] = (float)cos(ang);
  ts[i] = (float)sin(ang);
}

// ---------------- fp32 -> bf16 elementwise (x) ----------------
__global__ __launch_bounds__(256) void cvt_kernel(const float* __restrict__ in,
                                                  unsigned short* __restrict__ out, int n4) {
  int i = blockIdx.x * 256 + threadIdx.x;
  if (i >= n4) return;
  float4 v = ((const float4*)in)[i];
  short4v o;
  o[0] = (short)f2bf(v.x); o[1] = (short)f2bf(v.y);
  o[2] = (short)f2bf(v.z); o[3] = (short)f2bf(v.w);
  *(short4v*)&out[(size_t)i * 4] = o;
}

// ---------------- fp32 [R][C] -> bf16 [C][R] tiled transpose ----------------
__global__ __launch_bounds__(256) void transpose_cvt(const float* __restrict__ in,
                                                     unsigned short* __restrict__ out,
                                                     int R, int C) {
  __shared__ float tile[32][33];
  const int bx = blockIdx.x * 32, by = blockIdx.y * 32;
  const int tx = threadIdx.x & 31, ty0 = threadIdx.x >> 5;
#pragma unroll
  for (int p = 0; p < 4; ++p) {
    int r = ty0 + p * 8;
    tile[r][tx] = in[(size_t)(by + r) * C + bx + tx];
  }
  __syncthreads();
#pragma unroll
  for (int p = 0; p < 4; ++p) {
    int r = ty0 + p * 8;
    out[(size_t)(bx + r) * R + by + tx] = f2bf(tile[tx][r]);
  }
}

// ---------------- GEMM: C[M][N] = A[M][K](bf16) @ Bt[N][K](bf16)^T, fp32 out ----
// m97 structure: 128x128 tile, BK=32, 4 waves each 64x64, global_load_lds w=16.
__global__ __launch_bounds__(256) void gemm_bt(const unsigned short* __restrict__ A,
                                               const unsigned short* __restrict__ Bt,
                                               float* __restrict__ C,
                                               int M, int N, int K) {
  __shared__ unsigned short As[128 * 32];
  __shared__ unsigned short Bs[128 * 32];
  const int t = threadIdx.x, lane = t & 63, wv = t >> 6;
  const int bn = blockIdx.x, bm = blockIdx.y;
  const int m0 = bm * 128, n0 = bn * 128;
  f32x4 acc[4][4];
#pragma unroll
  for (int m = 0; m < 4; ++m)
#pragma unroll
    for (int n = 0; n < 4; ++n) acc[m][n] = (f32x4){0.f, 0.f, 0.f, 0.f};
  const int wr = (wv >> 1) * 64, wc = (wv & 1) * 64;
  const int ar = lane & 15, ak = (lane >> 4) * 8;
  const int srow = lane >> 2, skc = (lane & 3) * 8;
  const int nkt = K >> 5;
  for (int kt = 0; kt < nkt; ++kt) {
    const unsigned short* Ag = A + (size_t)m0 * K + kt * 32;
    const unsigned short* Bg = Bt + (size_t)n0 * K + kt * 32;
#pragma unroll
    for (int p = 0; p < 2; ++p) {
      int c = wv * 2 + p;
      async_load16(Ag + (size_t)(c * 16 + srow) * K + skc, &As[c * 512]);
      async_load16(Bg + (size_t)(c * 16 + srow) * K + skc, &Bs[c * 512]);
    }
    __syncthreads();
    bf16x8 af[4], bfr[4];
#pragma unroll
    for (int m = 0; m < 4; ++m) af[m] = *(const bf16x8*)&As[(wr + m * 16 + ar) * 32 + ak];
#pragma unroll
    for (int n = 0; n < 4; ++n) bfr[n] = *(const bf16x8*)&Bs[(wc + n * 16 + ar) * 32 + ak];
#pragma unroll
    for (int m = 0; m < 4; ++m)
#pragma unroll
      for (int n = 0; n < 4; ++n) acc[m][n] = MFMA16(af[m], bfr[n], acc[m][n]);
    __syncthreads();
  }
#pragma unroll
  for (int m = 0; m < 4; ++m) {
    int row = m0 + wr + m * 16 + (lane >> 4) * 4;
#pragma unroll
    for (int n = 0; n < 4; ++n) {
      int col = n0 + wc + n * 16 + ar;
      float* cp = C + (size_t)row * N + col;
#pragma unroll
      for (int j = 0; j < 4; ++j) cp[(size_t)j * N] = acc[m][n][j];
    }
  }
}

// ---------------- RoPE apply + head split + V transpose ----------------
// qkv fp32 [B*S][3072] -> q,k bf16 [B,H,S,64] (rope'd), vT bf16 [B,H,64,S]
__global__ __launch_bounds__(256) void rope_kernel(const float* __restrict__ qkv,
                                                   const float* __restrict__ tc,
                                                   const float* __restrict__ ts,
                                                   unsigned short* __restrict__ qo,
                                                   unsigned short* __restrict__ ko,
                                                   unsigned short* __restrict__ vt) {
  const int S = 2048;
  const int bx = blockIdx.x;
  const int st = bx & 31, bh = bx >> 5;
  const int b = bh >> 4, h = bh & 15;
  const int t = threadIdx.x;
  const int sl = t >> 2, j0 = (t & 3) * 8;
  const int s = st * 64 + sl;
  const float* row = qkv + (size_t)(b * S + s) * 3072;
  float cv[8], sv[8];
#pragma unroll
  for (int i = 0; i < 8; ++i) {
    cv[i] = tc[s * 32 + j0 + i];
    sv[i] = ts[s * 32 + j0 + i];
  }
  __shared__ unsigned short vtile[64][66];
#pragma unroll
  for (int m = 0; m < 2; ++m) {
    const int col0 = m * 1024 + h * 64;
    float lo[8], hi[8];
#pragma unroll
    for (int i = 0; i < 8; ++i) {
      lo[i] = row[col0 + j0 + i];
      hi[i] = row[col0 + 32 + j0 + i];
    }
    bf16x8 outlo, outhi;
#pragma unroll
    for (int i = 0; i < 8; ++i) {
      outlo[i] = (short)f2bf(lo[i] * cv[i] - hi[i] * sv[i]);
      outhi[i] = (short)f2bf(hi[i] * cv[i] + lo[i] * sv[i]);
    }
    unsigned short* dst = (m == 0 ? qo : ko) + (size_t)(bh * S + s) * 64;
    *(bf16x8*)&dst[j0] = outlo;
    *(bf16x8*)&dst[32 + j0] = outhi;
  }
  {
    const int col0 = 2048 + h * 64;
#pragma unroll
    for (int i = 0; i < 8; ++i) {
      vtile[j0 + i][sl] = f2bf(row[col0 + j0 + i]);
      vtile[j0 + 32 + i][sl] = f2bf(row[col0 + 32 + j0 + i]);
    }
  }
  __syncthreads();
  {
    const int hd = t >> 2, sc0 = (t & 3) * 16;
    unsigned short* dst = vt + ((size_t)bh * 64 + hd) * S + st * 64 + sc0;
    bf16x8 a, bv;
#pragma unroll
    for (int i = 0; i < 8; ++i) {
      a[i] = (short)vtile[hd][sc0 + i];
      bv[i] = (short)vtile[hd][sc0 + 8 + i];
    }
    *(bf16x8*)&dst[0] = a;
    *(bf16x8*)&dst[8] = bv;
  }
}

// ---------------- causal flash attention ----------------
// grid: B*H*(S/64); 4 waves/block, each wave owns 16 q-rows (independent).
// Q,K bf16 [B,H,S,64]; vT bf16 [B,H,64,S]; out bf16 [B*S][1024] (head-concat).
__global__ __launch_bounds__(256) void attn_kernel(const unsigned short* __restrict__ Q,
                                                   const unsigned short* __restrict__ Kk,
                                                   const unsigned short* __restrict__ Vt,
                                                   unsigned short* __restrict__ O) {
  const int S = 2048;
  const int t = threadIdx.x, lane = t & 63, wv = t >> 6;
  const int bx = blockIdx.x;
  const int qt = bx & 31, bh = bx >> 5;
  const int b = bh >> 4, h = bh & 15;
  const int qrow0 = qt * 64 + wv * 16;
  const int ar = lane & 15, ak = (lane >> 4) * 8;
  const int rl0 = (lane >> 4) * 4;
  const unsigned short* qh = Q + (size_t)bh * S * 64;
  const unsigned short* kh = Kk + (size_t)bh * S * 64;
  const unsigned short* vh = Vt + (size_t)bh * 64 * S;
  __shared__ unsigned short Plds[4][16][72];  // stride 72 -> b128 reads conflict-free

  bf16x8 qf[2];
#pragma unroll
  for (int kk = 0; kk < 2; ++kk)
    qf[kk] = *(const bf16x8*)&qh[(size_t)(qrow0 + ar) * 64 + kk * 32 + ak];

  f32x4 acc[4];
#pragma unroll
  for (int n = 0; n < 4; ++n) acc[n] = (f32x4){0.f, 0.f, 0.f, 0.f};
  float m_run[4] = {-INFINITY, -INFINITY, -INFINITY, -INFINITY};
  float l_run[4] = {0.f, 0.f, 0.f, 0.f};

  for (int kt = 0; kt <= qt; ++kt) {
    const unsigned short* kb = kh + (size_t)kt * 64 * 64;
    f32x4 sc[4];
#pragma unroll
    for (int n = 0; n < 4; ++n) {
      bf16x8 k0 = *(const bf16x8*)&kb[(n * 16 + ar) * 64 + ak];
      bf16x8 k1 = *(const bf16x8*)&kb[(n * 16 + ar) * 64 + 32 + ak];
      f32x4 z = (f32x4){0.f, 0.f, 0.f, 0.f};
      z = MFMA16(qf[0], k0, z);
      sc[n] = MFMA16(qf[1], k1, z);
    }
    float mx[4] = {-INFINITY, -INFINITY, -INFINITY, -INFINITY};
    const bool diag = (kt == qt);
#pragma unroll
    for (int n = 0; n < 4; ++n)
#pragma unroll
      for (int j = 0; j < 4; ++j) {
        float s = sc[n][j] * 0.125f;
        if (diag && (n * 16 + ar > wv * 16 + rl0 + j)) s = -INFINITY;
        sc[n][j] = s;
        mx[j] = fmaxf(mx[j], s);
      }
#pragma unroll
    for (int j = 0; j < 4; ++j) {
      float v = mx[j];
      v = fmaxf(v, __shfl_xor(v, 1));
      v = fmaxf(v, __shfl_xor(v, 2));
      v = fmaxf(v, __shfl_xor(v, 4));
      v = fmaxf(v, __shfl_xor(v, 8));
      mx[j] = v;
    }
    float scl[4];
#pragma unroll
    for (int j = 0; j < 4; ++j) {
      float mn = fmaxf(m_run[j], mx[j]);
      scl[j] = __expf(m_run[j] - mn);
      m_run[j] = mn;
    }
    float rs[4] = {0.f, 0.f, 0.f, 0.f};
#pragma unroll
    for (int n = 0; n < 4; ++n)
#pragma unroll
      for (int j = 0; j < 4; ++j) {
        float p = __expf(sc[n][j] - m_run[j]);
        sc[n][j] = p;
        rs[j] += p;
      }
#pragma unroll
    for (int j = 0; j < 4; ++j) {
      float v = rs[j];
      v += __shfl_xor(v, 1);
      v += __shfl_xor(v, 2);
      v += __shfl_xor(v, 4);
      v += __shfl_xor(v, 8);
      l_run[j] = l_run[j] * scl[j] + v;
    }
#pragma unroll
    for (int n = 0; n < 4; ++n)
#pragma unroll
      for (int j = 0; j < 4; ++j) acc[n][j] *= scl[j];
    // P (fp32 D-frag layout) -> bf16 -> LDS -> A-frag layout. Same-wave, no barrier.
#pragma unroll
    for (int n = 0; n < 4; ++n)
#pragma unroll
      for (int j = 0; j < 4; ++j) Plds[wv][rl0 + j][n * 16 + ar] = f2bf(sc[n][j]);
    bf16x8 pf[2];
#pragma unroll
    for (int kk = 0; kk < 2; ++kk)
      pf[kk] = *(const bf16x8*)&Plds[wv][ar][kk * 32 + ak];
    const unsigned short* vb = vh + kt * 64;
#pragma unroll
    for (int n = 0; n < 4; ++n) {
      bf16x8 v0 = *(const bf16x8*)&vb[(size_t)(n * 16 + ar) * S + ak];
      bf16x8 v1 = *(const bf16x8*)&vb[(size_t)(n * 16 + ar) * S + 32 + ak];
      acc[n] = MFMA16(pf[0], v0, acc[n]);
      acc[n] = MFMA16(pf[1], v1, acc[n]);
    }
  }
#pragma unroll
  for (int n = 0; n < 4; ++n)
#pragma unroll
    for (int j = 0; j < 4; ++j) {
      int row = qrow0 + rl0 + j;
      float o = acc[n][j] / l_run[j];
      O[(size_t)(b * S + row) * 1024 + h * 64 + n * 16 + ar] = f2bf(o);
    }
}

extern "C" void kernel_launch(void* const* d_in, const int* in_sizes, int n_in,
                              void* d_out, int out_size, void* d_ws, size_t ws_size,
                              hipStream_t stream) {
  const float* x = (const float*)d_in[0];
  const float* Wqkv = (const float*)d_in[1];
  const float* Wout = (const float*)d_in[2];
  float* out = (float*)d_out;

  char* ws = (char*)d_ws;
  size_t off = 0;
  auto take = [&](size_t bytes) {
    void* p = ws + off;
    off += (bytes + 255) & ~(size_t)255;
    return p;
  };
  float* tc = (float*)take(2048 * 32 * 4);
  float* tsn = (float*)take(2048 * 32 * 4);
  unsigned short* xbf = (unsigned short*)take((size_t)8192 * 1024 * 2);
  unsigned short* wqkvT = (unsigned short*)take((size_t)3072 * 1024 * 2);
  unsigned short* woutT = (unsigned short*)take((size_t)1024 * 1024 * 2);
  float* qkvf = (float*)take((size_t)8192 * 3072 * 4);
  unsigned short* qb = (unsigned short*)take((size_t)64 * 2048 * 64 * 2);
  unsigned short* kb = (unsigned short*)take((size_t)64 * 2048 * 64 * 2);
  unsigned short* vt = (unsigned short*)take((size_t)64 * 64 * 2048 * 2);
  unsigned short* attn = (unsigned short*)take((size_t)8192 * 1024 * 2);

  rope_table_kernel<<<256, 256, 0, stream>>>(tc, tsn);
  cvt_kernel<<<(2097152 + 255) / 256, 256, 0, stream>>>(x, xbf, 2097152);
  {
    dim3 g(96, 32);
    transpose_cvt<<<g, 256, 0, stream>>>(Wqkv, wqkvT, 1024, 3072);
  }
  {
    dim3 g(32, 32);
    transpose_cvt<<<g, 256, 0, stream>>>(Wout, woutT, 1024, 1024);
  }
  {
    dim3 g(24, 64);  // N/128, M/128
    gemm_bt<<<g, 256, 0, stream>>>(xbf, wqkvT, qkvf, 8192, 3072, 1024);
  }
  rope_kernel<<<2048, 256, 0, stream>>>(qkvf, tc, tsn, qb, kb, vt);
  attn_kernel<<<2048, 256, 0, stream>>>(qb, kb, vt, attn);
  {
    dim3 g(8, 64);
    gemm_bt<<<g, 256, 0, stream>>>(attn, woutT, out, 8192, 1024, 1024);
  }
}

// Round 2
// 396.673 us; speedup vs baseline: 1.5093x; 1.5093x over previous
//
#include <hip/hip_runtime.h>
#include <hip/hip_bf16.h>
#include <math.h>

typedef __attribute__((ext_vector_type(8))) short bf16x8;
typedef __attribute__((ext_vector_type(4))) short short4v;
typedef __attribute__((ext_vector_type(4))) float f32x4;
typedef __attribute__((ext_vector_type(16))) float f32x16;

#define MFMA16(a,b,c) __builtin_amdgcn_mfma_f32_16x16x32_bf16(a,b,c,0,0,0)
#define MFMA32(a,b,c) __builtin_amdgcn_mfma_f32_32x32x16_bf16(a,b,c,0,0,0)

__device__ __forceinline__ unsigned short f2bf(float f) {
  union { float f; unsigned u; } v; v.f = f;
  unsigned r = v.u + 0x7FFFu + ((v.u >> 16) & 1u);
  return (unsigned short)(r >> 16);
}

__device__ __forceinline__ void async_load16(const void* g, void* lds) {
  __builtin_amdgcn_global_load_lds(
      (const __attribute__((address_space(1))) unsigned int*)g,
      (__attribute__((address_space(3))) unsigned int*)lds, 16, 0, 0);
}

__device__ __forceinline__ f32x16 zero16() {
  f32x16 z;
#pragma unroll
  for (int i = 0; i < 16; ++i) z[i] = 0.f;
  return z;
}

// ---------------- RoPE table (fp64 for accuracy, one-shot) ----------------
__global__ void rope_table_kernel(float* __restrict__ tc, float* __restrict__ ts) {
  int i = blockIdx.x * 256 + threadIdx.x;
  if (i >= 2048 * 32) return;
  int s = i >> 5, j = i & 31;
  double invf = pow(10000.0, -(double)(2 * j) / 64.0);
  double ang = (double)s * invf;
  tc[i] = (float)cos(ang);
  ts[i] = (float)sin(ang);
}

// ---------------- fp32 -> bf16 elementwise (x) ----------------
__global__ __launch_bounds__(256) void cvt_kernel(const float* __restrict__ in,
                                                  unsigned short* __restrict__ out, int n4) {
  int i = blockIdx.x * 256 + threadIdx.x;
  if (i >= n4) return;
  float4 v = ((const float4*)in)[i];
  short4v o;
  o[0] = (short)f2bf(v.x); o[1] = (short)f2bf(v.y);
  o[2] = (short)f2bf(v.z); o[3] = (short)f2bf(v.w);
  *(short4v*)&out[(size_t)i * 4] = o;
}

// ---------------- fp32 [R][C] -> bf16 [C][R] tiled transpose ----------------
__global__ __launch_bounds__(256) void transpose_cvt(const float* __restrict__ in,
                                                     unsigned short* __restrict__ out,
                                                     int R, int C) {
  __shared__ float tile[32][33];
  const int bx = blockIdx.x * 32, by = blockIdx.y * 32;
  const int tx = threadIdx.x & 31, ty0 = threadIdx.x >> 5;
#pragma unroll
  for (int p = 0; p < 4; ++p) {
    int r = ty0 + p * 8;
    tile[r][tx] = in[(size_t)(by + r) * C + bx + tx];
  }
  __syncthreads();
#pragma unroll
  for (int p = 0; p < 4; ++p) {
    int r = ty0 + p * 8;
    out[(size_t)(bx + r) * R + by + tx] = f2bf(tile[tx][r]);
  }
}

// ---------------- GEMM: C[M][N] = A[M][K](bf16) @ Bt[N][K](bf16)^T, fp32 out ----
__global__ __launch_bounds__(256) void gemm_bt(const unsigned short* __restrict__ A,
                                               const unsigned short* __restrict__ Bt,
                                               float* __restrict__ C,
                                               int M, int N, int K) {
  __shared__ unsigned short As[128 * 32];
  __shared__ unsigned short Bs[128 * 32];
  const int t = threadIdx.x, lane = t & 63, wv = t >> 6;
  const int bn = blockIdx.x, bm = blockIdx.y;
  const int m0 = bm * 128, n0 = bn * 128;
  f32x4 acc[4][4];
#pragma unroll
  for (int m = 0; m < 4; ++m)
#pragma unroll
    for (int n = 0; n < 4; ++n) acc[m][n] = (f32x4){0.f, 0.f, 0.f, 0.f};
  const int wr = (wv >> 1) * 64, wc = (wv & 1) * 64;
  const int ar = lane & 15, ak = (lane >> 4) * 8;
  const int srow = lane >> 2, skc = (lane & 3) * 8;
  const int nkt = K >> 5;
  for (int kt = 0; kt < nkt; ++kt) {
    const unsigned short* Ag = A + (size_t)m0 * K + kt * 32;
    const unsigned short* Bg = Bt + (size_t)n0 * K + kt * 32;
#pragma unroll
    for (int p = 0; p < 2; ++p) {
      int c = wv * 2 + p;
      async_load16(Ag + (size_t)(c * 16 + srow) * K + skc, &As[c * 512]);
      async_load16(Bg + (size_t)(c * 16 + srow) * K + skc, &Bs[c * 512]);
    }
    __syncthreads();
    bf16x8 af[4], bfr[4];
#pragma unroll
    for (int m = 0; m < 4; ++m) af[m] = *(const bf16x8*)&As[(wr + m * 16 + ar) * 32 + ak];
#pragma unroll
    for (int n = 0; n < 4; ++n) bfr[n] = *(const bf16x8*)&Bs[(wc + n * 16 + ar) * 32 + ak];
#pragma unroll
    for (int m = 0; m < 4; ++m)
#pragma unroll
      for (int n = 0; n < 4; ++n) acc[m][n] = MFMA16(af[m], bfr[n], acc[m][n]);
    __syncthreads();
  }
#pragma unroll
  for (int m = 0; m < 4; ++m) {
    int row = m0 + wr + m * 16 + (lane >> 4) * 4;
#pragma unroll
    for (int n = 0; n < 4; ++n) {
      int col = n0 + wc + n * 16 + ar;
      float* cp = C + (size_t)row * N + col;
#pragma unroll
      for (int j = 0; j < 4; ++j) cp[(size_t)j * N] = acc[m][n][j];
    }
  }
}

// ---------------- RoPE apply + head split + V transpose ----------------
// qkv fp32 [B*S][3072] -> q (pre-scaled by 1/8), k bf16 [B,H,S,64]; vT bf16 [B,H,64,S]
__global__ __launch_bounds__(256) void rope_kernel(const float* __restrict__ qkv,
                                                   const float* __restrict__ tc,
                                                   const float* __restrict__ ts,
                                                   unsigned short* __restrict__ qo,
                                                   unsigned short* __restrict__ ko,
                                                   unsigned short* __restrict__ vt) {
  const int S = 2048;
  const int bx = blockIdx.x;
  const int st = bx & 31, bh = bx >> 5;
  const int b = bh >> 4, h = bh & 15;
  const int t = threadIdx.x;
  const int sl = t >> 2, j0 = (t & 3) * 8;
  const int s = st * 64 + sl;
  const float* row = qkv + (size_t)(b * S + s) * 3072;
  float cv[8], sv[8];
#pragma unroll
  for (int i = 0; i < 8; ++i) {
    cv[i] = tc[s * 32 + j0 + i];
    sv[i] = ts[s * 32 + j0 + i];
  }
  __shared__ unsigned short vtile[64][66];
#pragma unroll
  for (int m = 0; m < 2; ++m) {
    const int col0 = m * 1024 + h * 64;
    const float qscale = (m == 0) ? 0.125f : 1.0f;  // fold 1/sqrt(hd) into Q (exact pow2)
    float lo[8], hi[8];
#pragma unroll
    for (int i = 0; i < 8; ++i) {
      lo[i] = row[col0 + j0 + i];
      hi[i] = row[col0 + 32 + j0 + i];
    }
    bf16x8 outlo, outhi;
#pragma unroll
    for (int i = 0; i < 8; ++i) {
      outlo[i] = (short)f2bf((lo[i] * cv[i] - hi[i] * sv[i]) * qscale);
      outhi[i] = (short)f2bf((hi[i] * cv[i] + lo[i] * sv[i]) * qscale);
    }
    unsigned short* dst = (m == 0 ? qo : ko) + (size_t)(bh * S + s) * 64;
    *(bf16x8*)&dst[j0] = outlo;
    *(bf16x8*)&dst[32 + j0] = outhi;
  }
  {
    const int col0 = 2048 + h * 64;
#pragma unroll
    for (int i = 0; i < 8; ++i) {
      vtile[j0 + i][sl] = f2bf(row[col0 + j0 + i]);
      vtile[j0 + 32 + i][sl] = f2bf(row[col0 + 32 + j0 + i]);
    }
  }
  __syncthreads();
  {
    const int hd = t >> 2, sc0 = (t & 3) * 16;
    unsigned short* dst = vt + ((size_t)bh * 64 + hd) * S + st * 64 + sc0;
    bf16x8 a, bv;
#pragma unroll
    for (int i = 0; i < 8; ++i) {
      a[i] = (short)vtile[hd][sc0 + i];
      bv[i] = (short)vtile[hd][sc0 + 8 + i];
    }
    *(bf16x8*)&dst[0] = a;
    *(bf16x8*)&dst[8] = bv;
  }
}

// ---------------- causal flash attention, swapped-operand 32x32 ----------------
// S^T = mfma(K, Q): col(lane&31)=q, row(crow)=key -> per-lane scalar softmax.
// O^T = mfma(V^T, P^T): col=q -> per-lane scalar rescale.
// MODE: 0 = full tile, 1 = diagonal even (keys 32..63 all masked), 2 = diagonal odd.
template<int MODE>
__device__ __forceinline__ void attn_tile(
    const unsigned short* __restrict__ kb,   // kh + kt*64*64   [64 keys][64 dims]
    const unsigned short* __restrict__ vb,   // vh + kt*64      [64 dims][S keys]
    const bf16x8 qf[4], int ql, int hi,
    f32x16& acc0, f32x16& acc1, float& m_run, float& l_run) {
  const int S = 2048;
  f32x16 sc0 = zero16(), sc1 = zero16();
#pragma unroll
  for (int s = 0; s < 4; ++s) {
    bf16x8 k0 = *(const bf16x8*)&kb[ql * 64 + s * 16 + hi * 8];
    sc0 = MFMA32(k0, qf[s], sc0);
  }
  if (MODE != 1) {
#pragma unroll
    for (int s = 0; s < 4; ++s) {
      bf16x8 k1 = *(const bf16x8*)&kb[(32 + ql) * 64 + s * 16 + hi * 8];
      sc1 = MFMA32(k1, qf[s], sc1);
    }
  }
  // causal mask on the diagonal bank: key_local crow(r,hi) > q_local ql
  if (MODE != 0) {
#pragma unroll
    for (int r = 0; r < 16; ++r) {
      int key = (r & 3) + 8 * (r >> 2) + 4 * hi;
      if (key > ql) {
        if (MODE == 1) sc0[r] = -INFINITY; else sc1[r] = -INFINITY;
      }
    }
  }
  float mx = -INFINITY;
#pragma unroll
  for (int r = 0; r < 16; ++r) mx = fmaxf(mx, sc0[r]);
  if (MODE != 1) {
#pragma unroll
    for (int r = 0; r < 16; ++r) mx = fmaxf(mx, sc1[r]);
  }
  mx = fmaxf(mx, __shfl_xor(mx, 32));
  const float mn = fmaxf(m_run, mx);
  const float scl = __expf(m_run - mn);
  m_run = mn;
  float rs = 0.f;
#pragma unroll
  for (int r = 0; r < 16; ++r) { float e = __expf(sc0[r] - mn); sc0[r] = e; rs += e; }
  if (MODE != 1) {
#pragma unroll
    for (int r = 0; r < 16; ++r) { float e = __expf(sc1[r] - mn); sc1[r] = e; rs += e; }
  }
  rs += __shfl_xor(rs, 32);
  l_run = l_run * scl + rs;
#pragma unroll
  for (int r = 0; r < 16; ++r) { acc0[r] *= scl; acc1[r] *= scl; }
  // P^T -> bf16 A-frag words. P[q][k] lives at reg r=(c&3)+4*(c>>3) of half hi'=(c>>2)&1 (c=k%32).
  unsigned w[16];
#pragma unroll
  for (int i = 0; i < 8; ++i) w[i] = (unsigned)f2bf(sc0[2 * i]) | ((unsigned)f2bf(sc0[2 * i + 1]) << 16);
  if (MODE != 1) {
#pragma unroll
    for (int i = 0; i < 8; ++i) w[8 + i] = (unsigned)f2bf(sc1[2 * i]) | ((unsigned)f2bf(sc1[2 * i + 1]) << 16);
  }
  constexpr int NT = (MODE == 1) ? 2 : 4;
#pragma unroll
  for (int tt = 0; tt < NT; ++tt) {
    const int base = (tt & 1) * 4 + (tt >> 1) * 8;
    unsigned wA = w[base], wB = w[base + 1], wC = w[base + 2], wD = w[base + 3];
    unsigned s1v = __shfl_xor(hi ? wA : wC, 32);
    unsigned s2v = __shfl_xor(hi ? wB : wD, 32);
    union { unsigned u[4]; bf16x8 v; } pw;
    pw.u[0] = hi ? s1v : wA;
    pw.u[1] = hi ? s2v : wB;
    pw.u[2] = hi ? wC : s1v;
    pw.u[3] = hi ? wD : s2v;
    bf16x8 v0 = *(const bf16x8*)&vb[(size_t)ql * S + tt * 16 + hi * 8];
    bf16x8 v1 = *(const bf16x8*)&vb[(size_t)(32 + ql) * S + tt * 16 + hi * 8];
    acc0 = MFMA32(v0, pw.v, acc0);
    acc1 = MFMA32(v1, pw.v, acc1);
  }
}

// grid: 64 bh * 16 qb (reversed for load balance); 4 waves/block, 32 q-rows/wave; no LDS.
__global__ __launch_bounds__(256) void attn_kernel(const unsigned short* __restrict__ Q,
                                                   const unsigned short* __restrict__ Kk,
                                                   const unsigned short* __restrict__ Vt,
                                                   unsigned short* __restrict__ O) {
  const int S = 2048;
  const int t = threadIdx.x, lane = t & 63, wv = t >> 6;
  const int bx = blockIdx.x;
  const int bh = bx >> 4;
  const int qb = 15 - (bx & 15);
  const int b = bh >> 4, h = bh & 15;
  const int q0 = qb * 128 + wv * 32;
  const int ql = lane & 31, hi = lane >> 5;
  const unsigned short* qh = Q + (size_t)bh * S * 64;
  const unsigned short* kh = Kk + (size_t)bh * S * 64;
  const unsigned short* vh = Vt + (size_t)bh * 64 * S;

  bf16x8 qf[4];
#pragma unroll
  for (int s = 0; s < 4; ++s)
    qf[s] = *(const bf16x8*)&qh[(size_t)(q0 + ql) * 64 + s * 16 + hi * 8];

  f32x16 acc0 = zero16(), acc1 = zero16();
  float m_run = -INFINITY, l_run = 0.f;

  const int nfull = q0 >> 6;
  for (int kt = 0; kt < nfull; ++kt)
    attn_tile<0>(kh + (size_t)kt * 4096, vh + kt * 64, qf, ql, hi, acc0, acc1, m_run, l_run);
  if (((q0 >> 5) & 1) == 0)
    attn_tile<1>(kh + (size_t)nfull * 4096, vh + nfull * 64, qf, ql, hi, acc0, acc1, m_run, l_run);
  else
    attn_tile<2>(kh + (size_t)nfull * 4096, vh + nfull * 64, qf, ql, hi, acc0, acc1, m_run, l_run);

  const float inv = 1.f / l_run;
  unsigned short* orow = O + (size_t)(b * S + q0 + ql) * 1024 + h * 64;
#pragma unroll
  for (int r = 0; r < 16; ++r) {
    int d = (r & 3) + 8 * (r >> 2) + 4 * hi;
    orow[d] = f2bf(acc0[r] * inv);
    orow[32 + d] = f2bf(acc1[r] * inv);
  }
}

extern "C" void kernel_launch(void* const* d_in, const int* in_sizes, int n_in,
                              void* d_out, int out_size, void* d_ws, size_t ws_size,
                              hipStream_t stream) {
  const float* x = (const float*)d_in[0];
  const float* Wqkv = (const float*)d_in[1];
  const float* Wout = (const float*)d_in[2];
  float* out = (float*)d_out;

  char* ws = (char*)d_ws;
  size_t off = 0;
  auto take = [&](size_t bytes) {
    void* p = ws + off;
    off += (bytes + 255) & ~(size_t)255;
    return p;
  };
  float* tc = (float*)take(2048 * 32 * 4);
  float* tsn = (float*)take(2048 * 32 * 4);
  unsigned short* xbf = (unsigned short*)take((size_t)8192 * 1024 * 2);
  unsigned short* wqkvT = (unsigned short*)take((size_t)3072 * 1024 * 2);
  unsigned short* woutT = (unsigned short*)take((size_t)1024 * 1024 * 2);
  float* qkvf = (float*)take((size_t)8192 * 3072 * 4);
  unsigned short* qb_ = (unsigned short*)take((size_t)64 * 2048 * 64 * 2);
  unsigned short* kb_ = (unsigned short*)take((size_t)64 * 2048 * 64 * 2);
  unsigned short* vt = (unsigned short*)take((size_t)64 * 64 * 2048 * 2);
  unsigned short* attn = (unsigned short*)take((size_t)8192 * 1024 * 2);

  rope_table_kernel<<<256, 256, 0, stream>>>(tc, tsn);
  cvt_kernel<<<(2097152 + 255) / 256, 256, 0, stream>>>(x, xbf, 2097152);
  {
    dim3 g(96, 32);
    transpose_cvt<<<g, 256, 0, stream>>>(Wqkv, wqkvT, 1024, 3072);
  }
  {
    dim3 g(32, 32);
    transpose_cvt<<<g, 256, 0, stream>>>(Wout, woutT, 1024, 1024);
  }
  {
    dim3 g(24, 64);
    gemm_bt<<<g, 256, 0, stream>>>(xbf, wqkvT, qkvf, 8192, 3072, 1024);
  }
  rope_kernel<<<2048, 256, 0, stream>>>(qkvf, tc, tsn, qb_, kb_, vt);
  attn_kernel<<<1024, 256, 0, stream>>>(qb_, kb_, vt, attn);
  {
    dim3 g(8, 64);
    gemm_bt<<<g, 256, 0, stream>>>(attn, woutT, out, 8192, 1024, 1024);
  }
}

// Round 3
// 311.213 us; speedup vs baseline: 1.9237x; 1.2746x over previous
//
#include <hip/hip_runtime.h>
#include <hip/hip_bf16.h>
#include <math.h>

typedef __attribute__((ext_vector_type(8))) short bf16x8;
typedef __attribute__((ext_vector_type(4))) short short4v;
typedef __attribute__((ext_vector_type(4))) float f32x4;
typedef __attribute__((ext_vector_type(16))) float f32x16;

#define MFMA16(a,b,c) __builtin_amdgcn_mfma_f32_16x16x32_bf16(a,b,c,0,0,0)
#define MFMA32(a,b,c) __builtin_amdgcn_mfma_f32_32x32x16_bf16(a,b,c,0,0,0)

__device__ __forceinline__ unsigned short f2bf(float f) {
  union { float f; unsigned u; } v; v.f = f;
  unsigned r = v.u + 0x7FFFu + ((v.u >> 16) & 1u);
  return (unsigned short)(r >> 16);
}

__device__ __forceinline__ void async_load16(const void* g, void* lds) {
  __builtin_amdgcn_global_load_lds(
      (const __attribute__((address_space(1))) unsigned int*)g,
      (__attribute__((address_space(3))) unsigned int*)lds, 16, 0, 0);
}

__device__ __forceinline__ f32x16 zero16() {
  f32x16 z;
#pragma unroll
  for (int i = 0; i < 16; ++i) z[i] = 0.f;
  return z;
}

// ---------------- RoPE table ----------------
__global__ void rope_table_kernel(float* __restrict__ tc, float* __restrict__ ts) {
  int i = blockIdx.x * 256 + threadIdx.x;
  if (i >= 2048 * 32) return;
  int s = i >> 5, j = i & 31;
  double invf = pow(10000.0, -(double)(2 * j) / 64.0);
  double ang = (double)s * invf;
  tc[i] = (float)cos(ang);
  ts[i] = (float)sin(ang);
}

// ---------------- fp32 -> bf16 elementwise ----------------
__global__ __launch_bounds__(256) void cvt_kernel(const float* __restrict__ in,
                                                  unsigned short* __restrict__ out, int n4) {
  int i = blockIdx.x * 256 + threadIdx.x;
  if (i >= n4) return;
  float4 v = ((const float4*)in)[i];
  short4v o;
  o[0] = (short)f2bf(v.x); o[1] = (short)f2bf(v.y);
  o[2] = (short)f2bf(v.z); o[3] = (short)f2bf(v.w);
  *(short4v*)&out[(size_t)i * 4] = o;
}

// ---------------- fp32 [R][C] -> bf16 [C][R] transpose ----------------
__global__ __launch_bounds__(256) void transpose_cvt(const float* __restrict__ in,
                                                     unsigned short* __restrict__ out,
                                                     int R, int C) {
  __shared__ float tile[32][33];
  const int bx = blockIdx.x * 32, by = blockIdx.y * 32;
  const int tx = threadIdx.x & 31, ty0 = threadIdx.x >> 5;
#pragma unroll
  for (int p = 0; p < 4; ++p) {
    int r = ty0 + p * 8;
    tile[r][tx] = in[(size_t)(by + r) * C + bx + tx];
  }
  __syncthreads();
#pragma unroll
  for (int p = 0; p < 4; ++p) {
    int r = ty0 + p * 8;
    out[(size_t)(bx + r) * R + by + tx] = f2bf(tile[tx][r]);
  }
}

// ---------------- GEMM (m97 structure) ----------------
__global__ __launch_bounds__(256) void gemm_bt(const unsigned short* __restrict__ A,
                                               const unsigned short* __restrict__ Bt,
                                               float* __restrict__ C,
                                               int M, int N, int K) {
  __shared__ unsigned short As[128 * 32];
  __shared__ unsigned short Bs[128 * 32];
  const int t = threadIdx.x, lane = t & 63, wv = t >> 6;
  const int bn = blockIdx.x, bm = blockIdx.y;
  const int m0 = bm * 128, n0 = bn * 128;
  f32x4 acc[4][4];
#pragma unroll
  for (int m = 0; m < 4; ++m)
#pragma unroll
    for (int n = 0; n < 4; ++n) acc[m][n] = (f32x4){0.f, 0.f, 0.f, 0.f};
  const int wr = (wv >> 1) * 64, wc = (wv & 1) * 64;
  const int ar = lane & 15, ak = (lane >> 4) * 8;
  const int srow = lane >> 2, skc = (lane & 3) * 8;
  const int nkt = K >> 5;
  for (int kt = 0; kt < nkt; ++kt) {
    const unsigned short* Ag = A + (size_t)m0 * K + kt * 32;
    const unsigned short* Bg = Bt + (size_t)n0 * K + kt * 32;
#pragma unroll
    for (int p = 0; p < 2; ++p) {
      int c = wv * 2 + p;
      async_load16(Ag + (size_t)(c * 16 + srow) * K + skc, &As[c * 512]);
      async_load16(Bg + (size_t)(c * 16 + srow) * K + skc, &Bs[c * 512]);
    }
    __syncthreads();
    bf16x8 af[4], bfr[4];
#pragma unroll
    for (int m = 0; m < 4; ++m) af[m] = *(const bf16x8*)&As[(wr + m * 16 + ar) * 32 + ak];
#pragma unroll
    for (int n = 0; n < 4; ++n) bfr[n] = *(const bf16x8*)&Bs[(wc + n * 16 + ar) * 32 + ak];
#pragma unroll
    for (int m = 0; m < 4; ++m)
#pragma unroll
      for (int n = 0; n < 4; ++n) acc[m][n] = MFMA16(af[m], bfr[n], acc[m][n]);
    __syncthreads();
  }
#pragma unroll
  for (int m = 0; m < 4; ++m) {
    int row = m0 + wr + m * 16 + (lane >> 4) * 4;
#pragma unroll
    for (int n = 0; n < 4; ++n) {
      int col = n0 + wc + n * 16 + ar;
      float* cp = C + (size_t)row * N + col;
#pragma unroll
      for (int j = 0; j < 4; ++j) cp[(size_t)j * N] = acc[m][n][j];
    }
  }
}

// ---------------- RoPE apply + head split + V transpose ----------------
__global__ __launch_bounds__(256) void rope_kernel(const float* __restrict__ qkv,
                                                   const float* __restrict__ tc,
                                                   const float* __restrict__ ts,
                                                   unsigned short* __restrict__ qo,
                                                   unsigned short* __restrict__ ko,
                                                   unsigned short* __restrict__ vt) {
  const int S = 2048;
  const int bx = blockIdx.x;
  const int st = bx & 31, bh = bx >> 5;
  const int b = bh >> 4, h = bh & 15;
  const int t = threadIdx.x;
  const int sl = t >> 2, j0 = (t & 3) * 8;
  const int s = st * 64 + sl;
  const float* row = qkv + (size_t)(b * S + s) * 3072;
  float cv[8], sv[8];
#pragma unroll
  for (int i = 0; i < 8; ++i) {
    cv[i] = tc[s * 32 + j0 + i];
    sv[i] = ts[s * 32 + j0 + i];
  }
  __shared__ unsigned short vtile[64][66];
#pragma unroll
  for (int m = 0; m < 2; ++m) {
    const int col0 = m * 1024 + h * 64;
    const float qscale = (m == 0) ? 0.125f : 1.0f;
    float lo[8], hi[8];
#pragma unroll
    for (int i = 0; i < 8; ++i) {
      lo[i] = row[col0 + j0 + i];
      hi[i] = row[col0 + 32 + j0 + i];
    }
    bf16x8 outlo, outhi;
#pragma unroll
    for (int i = 0; i < 8; ++i) {
      outlo[i] = (short)f2bf((lo[i] * cv[i] - hi[i] * sv[i]) * qscale);
      outhi[i] = (short)f2bf((hi[i] * cv[i] + lo[i] * sv[i]) * qscale);
    }
    unsigned short* dst = (m == 0 ? qo : ko) + (size_t)(bh * S + s) * 64;
    *(bf16x8*)&dst[j0] = outlo;
    *(bf16x8*)&dst[32 + j0] = outhi;
  }
  {
    const int col0 = 2048 + h * 64;
#pragma unroll
    for (int i = 0; i < 8; ++i) {
      vtile[j0 + i][sl] = f2bf(row[col0 + j0 + i]);
      vtile[j0 + 32 + i][sl] = f2bf(row[col0 + 32 + j0 + i]);
    }
  }
  __syncthreads();
  {
    const int hd = t >> 2, sc0 = (t & 3) * 16;
    unsigned short* dst = vt + ((size_t)bh * 64 + hd) * S + st * 64 + sc0;
    bf16x8 a, bv;
#pragma unroll
    for (int i = 0; i < 8; ++i) {
      a[i] = (short)vtile[hd][sc0 + i];
      bv[i] = (short)vtile[hd][sc0 + 8 + i];
    }
    *(bf16x8*)&dst[0] = a;
    *(bf16x8*)&dst[8] = bv;
  }
}

// ---------------- attention: dual-chain swapped-operand 32x32 ----------------
// Each wave owns q rows [64m,64m+32) (chain A) and [64m+32,64m+64) (chain B).
// Both chains share every K/V tile load. Softmax stats are per-lane scalars.

__device__ __forceinline__ bf16x8 buildP(const unsigned* w, int tt, int hi) {
  const int base = (tt & 1) * 4 + (tt >> 1) * 8;
  unsigned wA = w[base], wB = w[base + 1], wC = w[base + 2], wD = w[base + 3];
  unsigned s1v = __shfl_xor(hi ? wA : wC, 32);
  unsigned s2v = __shfl_xor(hi ? wB : wD, 32);
  union { unsigned u[4]; bf16x8 v; } pw;
  pw.u[0] = hi ? s1v : wA;
  pw.u[1] = hi ? s2v : wB;
  pw.u[2] = hi ? wC : s1v;
  pw.u[3] = hi ? wD : s2v;
  return pw.v;
}

// softmax update + P->bf16 repack for one chain. BANKS=1: bank1 dead (diag even half).
template<int BANKS>
__device__ __forceinline__ void softmax_update(f32x16& s0, f32x16& s1,
                                               float& m_run, float& l_run,
                                               f32x16& a0, f32x16& a1, unsigned* w) {
  float mx = -INFINITY;
#pragma unroll
  for (int r = 0; r < 16; ++r) mx = fmaxf(mx, s0[r]);
  if (BANKS == 2) {
#pragma unroll
    for (int r = 0; r < 16; ++r) mx = fmaxf(mx, s1[r]);
  }
  mx = fmaxf(mx, __shfl_xor(mx, 32));
  const float mn = fmaxf(m_run, mx);
  const float scl = __expf(m_run - mn);
  m_run = mn;
  float rs = 0.f;
#pragma unroll
  for (int r = 0; r < 16; ++r) { float e = __expf(s0[r] - mn); s0[r] = e; rs += e; }
  if (BANKS == 2) {
#pragma unroll
    for (int r = 0; r < 16; ++r) { float e = __expf(s1[r] - mn); s1[r] = e; rs += e; }
  }
  rs += __shfl_xor(rs, 32);
  l_run = l_run * scl + rs;
#pragma unroll
  for (int r = 0; r < 16; ++r) { a0[r] *= scl; a1[r] *= scl; }
#pragma unroll
  for (int i = 0; i < 8; ++i)
    w[i] = (unsigned)f2bf(s0[2 * i]) | ((unsigned)f2bf(s0[2 * i + 1]) << 16);
  if (BANKS == 2) {
#pragma unroll
    for (int i = 0; i < 8; ++i)
      w[8 + i] = (unsigned)f2bf(s1[2 * i]) | ((unsigned)f2bf(s1[2 * i + 1]) << 16);
  }
}

// grid: 512 blocks (8 XCD-chunks x 64); block = (bh, j); waves take m in {j,31-j,15-j,16+j}
// -> every block is exactly 66 tiles of work. 2 blocks/CU, no LDS.
__global__ __launch_bounds__(256) void attn_kernel(const unsigned short* __restrict__ Q,
                                                   const unsigned short* __restrict__ Kk,
                                                   const unsigned short* __restrict__ Vt,
                                                   unsigned short* __restrict__ O) {
  const int S = 2048;
  const int t = threadIdx.x, lane = t & 63, wv = t >> 6;
  const int swz = (blockIdx.x & 7) * 64 + (blockIdx.x >> 3);  // XCD-contiguous
  const int bh = swz >> 3, j = swz & 7;
  const int b = bh >> 4, h = bh & 15;
  const int m = (wv & 1) ? ((wv & 2) ? 16 + j : 31 - j)
                         : ((wv & 2) ? 15 - j : j);
  const int q0 = m * 64;
  const int ql = lane & 31, hi = lane >> 5;
  const unsigned short* qh = Q + (size_t)bh * S * 64;
  const unsigned short* kh = Kk + (size_t)bh * S * 64;
  const unsigned short* vh = Vt + (size_t)bh * 64 * S;

  bf16x8 qfA[4], qfB[4];
#pragma unroll
  for (int s = 0; s < 4; ++s) {
    qfA[s] = *(const bf16x8*)&qh[(size_t)(q0 + ql) * 64 + s * 16 + hi * 8];
    qfB[s] = *(const bf16x8*)&qh[(size_t)(q0 + 32 + ql) * 64 + s * 16 + hi * 8];
  }

  f32x16 aA0 = zero16(), aA1 = zero16(), aB0 = zero16(), aB1 = zero16();
  float mA = -INFINITY, lA = 0.f, mB = -INFINITY, lB = 0.f;

  // -------- shared full tiles --------
  for (int kt = 0; kt < m; ++kt) {
    const unsigned short* kb = kh + (size_t)kt * 4096;
    const unsigned short* vb = vh + kt * 64;
    bf16x8 k0[4], k1[4];
#pragma unroll
    for (int s = 0; s < 4; ++s) {
      k0[s] = *(const bf16x8*)&kb[ql * 64 + s * 16 + hi * 8];
      k1[s] = *(const bf16x8*)&kb[(32 + ql) * 64 + s * 16 + hi * 8];
    }
    unsigned wA[16], wB[16];
    {
      f32x16 s0 = zero16(), s1 = zero16();
#pragma unroll
      for (int s = 0; s < 4; ++s) {
        s0 = MFMA32(k0[s], qfA[s], s0);
        s1 = MFMA32(k1[s], qfA[s], s1);
      }
      softmax_update<2>(s0, s1, mA, lA, aA0, aA1, wA);
    }
    {
      f32x16 s0 = zero16(), s1 = zero16();
#pragma unroll
      for (int s = 0; s < 4; ++s) {
        s0 = MFMA32(k0[s], qfB[s], s0);
        s1 = MFMA32(k1[s], qfB[s], s1);
      }
      softmax_update<2>(s0, s1, mB, lB, aB0, aB1, wB);
    }
#pragma unroll
    for (int tt = 0; tt < 4; ++tt) {
      bf16x8 v0 = *(const bf16x8*)&vb[(size_t)ql * S + tt * 16 + hi * 8];
      bf16x8 v1 = *(const bf16x8*)&vb[(size_t)(32 + ql) * S + tt * 16 + hi * 8];
      bf16x8 pA = buildP(wA, tt, hi), pB = buildP(wB, tt, hi);
      aA0 = MFMA32(v0, pA, aA0);
      aA1 = MFMA32(v1, pA, aA1);
      aB0 = MFMA32(v0, pB, aB0);
      aB1 = MFMA32(v1, pB, aB1);
    }
  }

  // -------- shared diagonal tile (kt == m) --------
  {
    const unsigned short* kb = kh + (size_t)m * 4096;
    const unsigned short* vb = vh + m * 64;
    bf16x8 k0[4], k1[4];
#pragma unroll
    for (int s = 0; s < 4; ++s) {
      k0[s] = *(const bf16x8*)&kb[ql * 64 + s * 16 + hi * 8];
      k1[s] = *(const bf16x8*)&kb[(32 + ql) * 64 + s * 16 + hi * 8];
    }
    unsigned wA[16], wB[16];
    {  // chain A: keys 0..31 masked key>ql; bank1 fully masked
      f32x16 s0 = zero16(), s1;
#pragma unroll
      for (int s = 0; s < 4; ++s) s0 = MFMA32(k0[s], qfA[s], s0);
#pragma unroll
      for (int r = 0; r < 16; ++r) {
        int key = (r & 3) + 8 * (r >> 2) + 4 * hi;
        if (key > ql) s0[r] = -INFINITY;
      }
      softmax_update<1>(s0, s1, mA, lA, aA0, aA1, wA);
    }
    {  // chain B: bank0 fully visible; bank1 masked key>ql
      f32x16 s0 = zero16(), s1 = zero16();
#pragma unroll
      for (int s = 0; s < 4; ++s) {
        s0 = MFMA32(k0[s], qfB[s], s0);
        s1 = MFMA32(k1[s], qfB[s], s1);
      }
#pragma unroll
      for (int r = 0; r < 16; ++r) {
        int key = (r & 3) + 8 * (r >> 2) + 4 * hi;
        if (key > ql) s1[r] = -INFINITY;
      }
      softmax_update<2>(s0, s1, mB, lB, aB0, aB1, wB);
    }
#pragma unroll
    for (int tt = 0; tt < 2; ++tt) {  // keys 0..31: both chains
      bf16x8 v0 = *(const bf16x8*)&vb[(size_t)ql * S + tt * 16 + hi * 8];
      bf16x8 v1 = *(const bf16x8*)&vb[(size_t)(32 + ql) * S + tt * 16 + hi * 8];
      bf16x8 pA = buildP(wA, tt, hi), pB = buildP(wB, tt, hi);
      aA0 = MFMA32(v0, pA, aA0);
      aA1 = MFMA32(v1, pA, aA1);
      aB0 = MFMA32(v0, pB, aB0);
      aB1 = MFMA32(v1, pB, aB1);
    }
#pragma unroll
    for (int tt = 2; tt < 4; ++tt) {  // keys 32..63: chain B only
      bf16x8 v0 = *(const bf16x8*)&vb[(size_t)ql * S + tt * 16 + hi * 8];
      bf16x8 v1 = *(const bf16x8*)&vb[(size_t)(32 + ql) * S + tt * 16 + hi * 8];
      bf16x8 pB = buildP(wB, tt, hi);
      aB0 = MFMA32(v0, pB, aB0);
      aB1 = MFMA32(v1, pB, aB1);
    }
  }

  const float invA = 1.f / lA, invB = 1.f / lB;
  unsigned short* orowA = O + (size_t)(b * S + q0 + ql) * 1024 + h * 64;
  unsigned short* orowB = O + (size_t)(b * S + q0 + 32 + ql) * 1024 + h * 64;
#pragma unroll
  for (int r = 0; r < 16; ++r) {
    int d = (r & 3) + 8 * (r >> 2) + 4 * hi;
    orowA[d] = f2bf(aA0[r] * invA);
    orowA[32 + d] = f2bf(aA1[r] * invA);
    orowB[d] = f2bf(aB0[r] * invB);
    orowB[32 + d] = f2bf(aB1[r] * invB);
  }
}

extern "C" void kernel_launch(void* const* d_in, const int* in_sizes, int n_in,
                              void* d_out, int out_size, void* d_ws, size_t ws_size,
                              hipStream_t stream) {
  const float* x = (const float*)d_in[0];
  const float* Wqkv = (const float*)d_in[1];
  const float* Wout = (const float*)d_in[2];
  float* out = (float*)d_out;

  char* ws = (char*)d_ws;
  size_t off = 0;
  auto take = [&](size_t bytes) {
    void* p = ws + off;
    off += (bytes + 255) & ~(size_t)255;
    return p;
  };
  float* tc = (float*)take(2048 * 32 * 4);
  float* tsn = (float*)take(2048 * 32 * 4);
  unsigned short* xbf = (unsigned short*)take((size_t)8192 * 1024 * 2);
  unsigned short* wqkvT = (unsigned short*)take((size_t)3072 * 1024 * 2);
  unsigned short* woutT = (unsigned short*)take((size_t)1024 * 1024 * 2);
  float* qkvf = (float*)take((size_t)8192 * 3072 * 4);
  unsigned short* qb_ = (unsigned short*)take((size_t)64 * 2048 * 64 * 2);
  unsigned short* kb_ = (unsigned short*)take((size_t)64 * 2048 * 64 * 2);
  unsigned short* vt = (unsigned short*)take((size_t)64 * 64 * 2048 * 2);
  unsigned short* attn = (unsigned short*)take((size_t)8192 * 1024 * 2);

  rope_table_kernel<<<256, 256, 0, stream>>>(tc, tsn);
  cvt_kernel<<<(2097152 + 255) / 256, 256, 0, stream>>>(x, xbf, 2097152);
  {
    dim3 g(96, 32);
    transpose_cvt<<<g, 256, 0, stream>>>(Wqkv, wqkvT, 1024, 3072);
  }
  {
    dim3 g(32, 32);
    transpose_cvt<<<g, 256, 0, stream>>>(Wout, woutT, 1024, 1024);
  }
  {
    dim3 g(24, 64);
    gemm_bt<<<g, 256, 0, stream>>>(xbf, wqkvT, qkvf, 8192, 3072, 1024);
  }
  rope_kernel<<<2048, 256, 0, stream>>>(qkvf, tc, tsn, qb_, kb_, vt);
  attn_kernel<<<512, 256, 0, stream>>>(qb_, kb_, vt, attn);
  {
    dim3 g(8, 64);
    gemm_bt<<<g, 256, 0, stream>>>(attn, woutT, out, 8192, 1024, 1024);
  }
}

// Round 5
// 282.811 us; speedup vs baseline: 2.1169x; 1.1004x over previous
//
#include <hip/hip_runtime.h>
#include <hip/hip_bf16.h>
#include <math.h>

typedef __attribute__((ext_vector_type(8))) short bf16x8;
typedef __attribute__((ext_vector_type(4))) short short4v;
typedef __attribute__((ext_vector_type(4))) float f32x4;
typedef __attribute__((ext_vector_type(16))) float f32x16;

#define MFMA16(a,b,c) __builtin_amdgcn_mfma_f32_16x16x32_bf16(a,b,c,0,0,0)
#define MFMA32(a,b,c) __builtin_amdgcn_mfma_f32_32x32x16_bf16(a,b,c,0,0,0)

__device__ __forceinline__ unsigned short f2bf(float f) {
  union { float f; unsigned u; } v; v.f = f;
  unsigned r = v.u + 0x7FFFu + ((v.u >> 16) & 1u);
  return (unsigned short)(r >> 16);
}

__device__ __forceinline__ unsigned cvt_pk(float lo, float hi) {
  unsigned r;
  asm("v_cvt_pk_bf16_f32 %0, %1, %2" : "=v"(r) : "v"(lo), "v"(hi));
  return r;
}

__device__ __forceinline__ void async_load16(const void* g, void* lds) {
  __builtin_amdgcn_global_load_lds(
      (const __attribute__((address_space(1))) unsigned int*)g,
      (__attribute__((address_space(3))) unsigned int*)lds, 16, 0, 0);
}

__device__ __forceinline__ f32x16 zero16() {
  f32x16 z;
#pragma unroll
  for (int i = 0; i < 16; ++i) z[i] = 0.f;
  return z;
}

// ---------------- RoPE table ----------------
__global__ void rope_table_kernel(float* __restrict__ tc, float* __restrict__ ts) {
  int i = blockIdx.x * 256 + threadIdx.x;
  if (i >= 2048 * 32) return;
  int s = i >> 5, j = i & 31;
  double invf = pow(10000.0, -(double)(2 * j) / 64.0);
  double ang = (double)s * invf;
  tc[i] = (float)cos(ang);
  ts[i] = (float)sin(ang);
}

// ---------------- fp32 -> bf16 elementwise ----------------
__global__ __launch_bounds__(256) void cvt_kernel(const float* __restrict__ in,
                                                  unsigned short* __restrict__ out, int n4) {
  int i = blockIdx.x * 256 + threadIdx.x;
  if (i >= n4) return;
  float4 v = ((const float4*)in)[i];
  short4v o;
  o[0] = (short)f2bf(v.x); o[1] = (short)f2bf(v.y);
  o[2] = (short)f2bf(v.z); o[3] = (short)f2bf(v.w);
  *(short4v*)&out[(size_t)i * 4] = o;
}

// ---------------- fp32 [R][C] -> bf16 [C][R] transpose ----------------
__global__ __launch_bounds__(256) void transpose_cvt(const float* __restrict__ in,
                                                     unsigned short* __restrict__ out,
                                                     int R, int C) {
  __shared__ float tile[32][33];
  const int bx = blockIdx.x * 32, by = blockIdx.y * 32;
  const int tx = threadIdx.x & 31, ty0 = threadIdx.x >> 5;
#pragma unroll
  for (int p = 0; p < 4; ++p) {
    int r = ty0 + p * 8;
    tile[r][tx] = in[(size_t)(by + r) * C + bx + tx];
  }
  __syncthreads();
#pragma unroll
  for (int p = 0; p < 4; ++p) {
    int r = ty0 + p * 8;
    out[(size_t)(bx + r) * R + by + tx] = f2bf(tile[tx][r]);
  }
}

// ---------------- GEMM (m97 structure) ----------------
__global__ __launch_bounds__(256) void gemm_bt(const unsigned short* __restrict__ A,
                                               const unsigned short* __restrict__ Bt,
                                               float* __restrict__ C,
                                               int M, int N, int K) {
  __shared__ unsigned short As[128 * 32];
  __shared__ unsigned short Bs[128 * 32];
  const int t = threadIdx.x, lane = t & 63, wv = t >> 6;
  const int bn = blockIdx.x, bm = blockIdx.y;
  const int m0 = bm * 128, n0 = bn * 128;
  f32x4 acc[4][4];
#pragma unroll
  for (int m = 0; m < 4; ++m)
#pragma unroll
    for (int n = 0; n < 4; ++n) acc[m][n] = (f32x4){0.f, 0.f, 0.f, 0.f};
  const int wr = (wv >> 1) * 64, wc = (wv & 1) * 64;
  const int ar = lane & 15, ak = (lane >> 4) * 8;
  const int srow = lane >> 2, skc = (lane & 3) * 8;
  const int nkt = K >> 5;
  for (int kt = 0; kt < nkt; ++kt) {
    const unsigned short* Ag = A + (size_t)m0 * K + kt * 32;
    const unsigned short* Bg = Bt + (size_t)n0 * K + kt * 32;
#pragma unroll
    for (int p = 0; p < 2; ++p) {
      int c = wv * 2 + p;
      async_load16(Ag + (size_t)(c * 16 + srow) * K + skc, &As[c * 512]);
      async_load16(Bg + (size_t)(c * 16 + srow) * K + skc, &Bs[c * 512]);
    }
    __syncthreads();
    bf16x8 af[4], bfr[4];
#pragma unroll
    for (int m = 0; m < 4; ++m) af[m] = *(const bf16x8*)&As[(wr + m * 16 + ar) * 32 + ak];
#pragma unroll
    for (int n = 0; n < 4; ++n) bfr[n] = *(const bf16x8*)&Bs[(wc + n * 16 + ar) * 32 + ak];
#pragma unroll
    for (int m = 0; m < 4; ++m)
#pragma unroll
      for (int n = 0; n < 4; ++n) acc[m][n] = MFMA16(af[m], bfr[n], acc[m][n]);
    __syncthreads();
  }
#pragma unroll
  for (int m = 0; m < 4; ++m) {
    int row = m0 + wr + m * 16 + (lane >> 4) * 4;
#pragma unroll
    for (int n = 0; n < 4; ++n) {
      int col = n0 + wc + n * 16 + ar;
      float* cp = C + (size_t)row * N + col;
#pragma unroll
      for (int j = 0; j < 4; ++j) cp[(size_t)j * N] = acc[m][n][j];
    }
  }
}

// ---------------- RoPE apply + head split + V transpose ----------------
// Q gets 0.125 * log2(e) prescale (softmax runs in exp2 domain).
__global__ __launch_bounds__(256) void rope_kernel(const float* __restrict__ qkv,
                                                   const float* __restrict__ tc,
                                                   const float* __restrict__ ts,
                                                   unsigned short* __restrict__ qo,
                                                   unsigned short* __restrict__ ko,
                                                   unsigned short* __restrict__ vt) {
  const int S = 2048;
  const int bx = blockIdx.x;
  const int st = bx & 31, bh = bx >> 5;
  const int b = bh >> 4, h = bh & 15;
  const int t = threadIdx.x;
  const int sl = t >> 2, j0 = (t & 3) * 8;
  const int s = st * 64 + sl;
  const float* row = qkv + (size_t)(b * S + s) * 3072;
  float cv[8], sv[8];
#pragma unroll
  for (int i = 0; i < 8; ++i) {
    cv[i] = tc[s * 32 + j0 + i];
    sv[i] = ts[s * 32 + j0 + i];
  }
  __shared__ unsigned short vtile[64][66];
#pragma unroll
  for (int m = 0; m < 2; ++m) {
    const int col0 = m * 1024 + h * 64;
    const float qscale = (m == 0) ? 0.125f * 1.44269504088896340736f : 1.0f;
    float lo[8], hi[8];
#pragma unroll
    for (int i = 0; i < 8; ++i) {
      lo[i] = row[col0 + j0 + i];
      hi[i] = row[col0 + 32 + j0 + i];
    }
    bf16x8 outlo, outhi;
#pragma unroll
    for (int i = 0; i < 8; ++i) {
      outlo[i] = (short)f2bf((lo[i] * cv[i] - hi[i] * sv[i]) * qscale);
      outhi[i] = (short)f2bf((hi[i] * cv[i] + lo[i] * sv[i]) * qscale);
    }
    unsigned short* dst = (m == 0 ? qo : ko) + (size_t)(bh * S + s) * 64;
    *(bf16x8*)&dst[j0] = outlo;
    *(bf16x8*)&dst[32 + j0] = outhi;
  }
  {
    const int col0 = 2048 + h * 64;
#pragma unroll
    for (int i = 0; i < 8; ++i) {
      vtile[j0 + i][sl] = f2bf(row[col0 + j0 + i]);
      vtile[j0 + 32 + i][sl] = f2bf(row[col0 + 32 + j0 + i]);
    }
  }
  __syncthreads();
  {
    const int hd = t >> 2, sc0 = (t & 3) * 16;
    unsigned short* dst = vt + ((size_t)bh * 64 + hd) * S + st * 64 + sc0;
    bf16x8 a, bv;
#pragma unroll
    for (int i = 0; i < 8; ++i) {
      a[i] = (short)vtile[hd][sc0 + i];
      bv[i] = (short)vtile[hd][sc0 + 8 + i];
    }
    *(bf16x8*)&dst[0] = a;
    *(bf16x8*)&dst[8] = bv;
  }
}

// ---------------- attention ----------------
// Each wave: chain A = q-group gA (32 rows), chain B = gB = 63-gA -> exactly
// 33 chain-tile units per wave (perfect balance). Swapped-operand 32x32 MFMA;
// per-lane scalar softmax in exp2 domain; cross-half traffic via __shfl_xor(32)
// (proven primitive); P-pack via v_cvt_pk_bf16_f32.

__device__ __forceinline__ bf16x8 buildP(const unsigned* w, int tt, int hi) {
  const int base = (tt & 1) * 4 + (tt >> 1) * 8;
  unsigned wA = w[base], wB = w[base + 1], wC = w[base + 2], wD = w[base + 3];
  unsigned s1v = __shfl_xor(hi ? wA : wC, 32);
  unsigned s2v = __shfl_xor(hi ? wB : wD, 32);
  union { unsigned u[4]; bf16x8 v; } pw;
  pw.u[0] = hi ? s1v : wA;
  pw.u[1] = hi ? s2v : wB;
  pw.u[2] = hi ? wC : s1v;
  pw.u[3] = hi ? wD : s2v;
  return pw.v;
}

// softmax update for one chain. l_run holds per-lane HALF sums (pair-summed at
// epilogue). BANKS=1: bank1 dead (even-g diagonal).
template<int BANKS>
__device__ __forceinline__ void softmax_chain(f32x16& s0, f32x16& s1,
                                              float& m_run, float& l_run,
                                              f32x16& a0, f32x16& a1, unsigned* w) {
  float p[8];
#pragma unroll
  for (int i = 0; i < 8; ++i) p[i] = fmaxf(s0[2 * i], s0[2 * i + 1]);
  if (BANKS == 2) {
#pragma unroll
    for (int i = 0; i < 8; ++i) p[i] = fmaxf(p[i], fmaxf(s1[2 * i], s1[2 * i + 1]));
  }
#pragma unroll
  for (int i = 0; i < 4; ++i) p[i] = fmaxf(p[i], p[i + 4]);
  float mx = fmaxf(fmaxf(p[0], p[1]), fmaxf(p[2], p[3]));
  mx = fmaxf(mx, __shfl_xor(mx, 32));  // pair-uniform max over all 32 keys
  const bool defer = __all(mx - m_run <= 8.0f) != 0;
  const float mn = defer ? m_run : fmaxf(m_run, mx);
  float r0 = 0.f, r1 = 0.f, r2 = 0.f, r3 = 0.f;
#pragma unroll
  for (int i = 0; i < 4; ++i) {
    float e0 = exp2f(s0[4 * i + 0] - mn); s0[4 * i + 0] = e0; r0 += e0;
    float e1 = exp2f(s0[4 * i + 1] - mn); s0[4 * i + 1] = e1; r1 += e1;
    float e2 = exp2f(s0[4 * i + 2] - mn); s0[4 * i + 2] = e2; r2 += e2;
    float e3 = exp2f(s0[4 * i + 3] - mn); s0[4 * i + 3] = e3; r3 += e3;
  }
  if (BANKS == 2) {
#pragma unroll
    for (int i = 0; i < 4; ++i) {
      float e0 = exp2f(s1[4 * i + 0] - mn); s1[4 * i + 0] = e0; r0 += e0;
      float e1 = exp2f(s1[4 * i + 1] - mn); s1[4 * i + 1] = e1; r1 += e1;
      float e2 = exp2f(s1[4 * i + 2] - mn); s1[4 * i + 2] = e2; r2 += e2;
      float e3 = exp2f(s1[4 * i + 3] - mn); s1[4 * i + 3] = e3; r3 += e3;
    }
  }
  const float rs = (r0 + r1) + (r2 + r3);  // per-lane half-sum
  if (defer) {
    l_run += rs;
  } else {
    const float scl = exp2f(m_run - mn);
    m_run = mn;
    l_run = l_run * scl + rs;
#pragma unroll
    for (int r = 0; r < 16; ++r) { a0[r] *= scl; a1[r] *= scl; }
  }
#pragma unroll
  for (int i = 0; i < 8; ++i) w[i] = cvt_pk(s0[2 * i], s0[2 * i + 1]);
  if (BANKS == 2) {
#pragma unroll
    for (int i = 0; i < 8; ++i) w[8 + i] = cvt_pk(s1[2 * i], s1[2 * i + 1]);
  }
}

// CA/CB: 0=off, 1=full, 2=diag(even g: bank1 dead), 3=diag(odd g: bank1 masked)
template<int CA, int CB>
__device__ __forceinline__ void tile_body(
    const unsigned short* __restrict__ kb, const unsigned short* __restrict__ vb,
    int ql, int hi,
    const bf16x8 (&qfA)[4], f32x16& aA0, f32x16& aA1, float& mA, float& lA,
    const bf16x8 (&qfB)[4], f32x16& aB0, f32x16& aB1, float& mB, float& lB) {
  constexpr bool A_on = CA != 0, B_on = CB != 0;
  constexpr bool A_b1 = (CA == 1 || CA == 3);
  constexpr bool B_b1 = (CB == 1 || CB == 3);
  constexpr bool k1need = A_b1 || B_b1;
  constexpr int NTT = k1need ? 4 : 2;
  constexpr int NTA = (CA == 2) ? 2 : 4;
  constexpr int NTB = (CB == 2) ? 2 : 4;
  const int S = 2048;

  bf16x8 k0[4], k1[4];
#pragma unroll
  for (int s = 0; s < 4; ++s) {
    k0[s] = *(const bf16x8*)&kb[ql * 64 + s * 16 + hi * 8];
    if (k1need) k1[s] = *(const bf16x8*)&kb[(32 + ql) * 64 + s * 16 + hi * 8];
  }

  f32x16 sA0, sA1, sB0, sB1;
  __builtin_amdgcn_s_setprio(1);
  if constexpr (A_on) {
    sA0 = zero16();
    if constexpr (A_b1) sA1 = zero16();
#pragma unroll
    for (int s = 0; s < 4; ++s) {
      sA0 = MFMA32(k0[s], qfA[s], sA0);
      if constexpr (A_b1) sA1 = MFMA32(k1[s], qfA[s], sA1);
    }
  }
  if constexpr (B_on) {
    sB0 = zero16();
    if constexpr (B_b1) sB1 = zero16();
#pragma unroll
    for (int s = 0; s < 4; ++s) {
      sB0 = MFMA32(k0[s], qfB[s], sB0);
      if constexpr (B_b1) sB1 = MFMA32(k1[s], qfB[s], sB1);
    }
  }
  __builtin_amdgcn_s_setprio(0);

  // V fragments early: latency hides under softmax VALU
  bf16x8 v0[4], v1[4];
#pragma unroll
  for (int tt = 0; tt < NTT; ++tt) {
    v0[tt] = *(const bf16x8*)&vb[(size_t)ql * S + tt * 16 + hi * 8];
    v1[tt] = *(const bf16x8*)&vb[(size_t)(32 + ql) * S + tt * 16 + hi * 8];
  }

  if constexpr (CA == 2 || CA == 3) {
#pragma unroll
    for (int r = 0; r < 16; ++r) {
      int key = (r & 3) + 8 * (r >> 2) + 4 * hi;
      if (key > ql) { if (CA == 2) sA0[r] = -INFINITY; else sA1[r] = -INFINITY; }
    }
  }
  if constexpr (CB == 2 || CB == 3) {
#pragma unroll
    for (int r = 0; r < 16; ++r) {
      int key = (r & 3) + 8 * (r >> 2) + 4 * hi;
      if (key > ql) { if (CB == 2) sB0[r] = -INFINITY; else sB1[r] = -INFINITY; }
    }
  }

  unsigned wA[16], wB[16];
  if constexpr (A_on) softmax_chain<A_b1 ? 2 : 1>(sA0, sA1, mA, lA, aA0, aA1, wA);
  if constexpr (B_on) softmax_chain<B_b1 ? 2 : 1>(sB0, sB1, mB, lB, aB0, aB1, wB);

  __builtin_amdgcn_s_setprio(1);
#pragma unroll
  for (int tt = 0; tt < NTT; ++tt) {
    if constexpr (A_on) {
      if (tt < NTA) {
        bf16x8 pA = buildP(wA, tt, hi);
        aA0 = MFMA32(v0[tt], pA, aA0);
        aA1 = MFMA32(v1[tt], pA, aA1);
      }
    }
    if constexpr (B_on) {
      if (tt < NTB) {
        bf16x8 pB = buildP(wB, tt, hi);
        aB0 = MFMA32(v0[tt], pB, aB0);
        aB1 = MFMA32(v1[tt], pB, aB1);
      }
    }
  }
  __builtin_amdgcn_s_setprio(0);
}

// grid: 512 blocks (XCD-swizzled); wave (bh, idx): chains gA=idx, gB=63-idx.
__global__ __launch_bounds__(256, 2) void attn_kernel(const unsigned short* __restrict__ Q,
                                                      const unsigned short* __restrict__ Kk,
                                                      const unsigned short* __restrict__ Vt,
                                                      unsigned short* __restrict__ O) {
  const int S = 2048;
  const int t = threadIdx.x, lane = t & 63, wv = t >> 6;
  const int swz = (blockIdx.x & 7) * 64 + (blockIdx.x >> 3);  // XCD-contiguous
  const int bh = swz >> 3, jj = swz & 7;
  const int b = bh >> 4, h = bh & 15;
  const int idx = jj * 4 + wv;          // 0..31
  const int gA = idx, gB = 63 - idx;
  const int kA = gA >> 1, kB = gB >> 1;
  const int ql = lane & 31, hi = lane >> 5;
  const unsigned short* qh = Q + (size_t)bh * S * 64;
  const unsigned short* kh = Kk + (size_t)bh * S * 64;
  const unsigned short* vh = Vt + (size_t)bh * 64 * S;

  bf16x8 qfA[4], qfB[4];
#pragma unroll
  for (int s = 0; s < 4; ++s) {
    qfA[s] = *(const bf16x8*)&qh[(size_t)(32 * gA + ql) * 64 + s * 16 + hi * 8];
    qfB[s] = *(const bf16x8*)&qh[(size_t)(32 * gB + ql) * 64 + s * 16 + hi * 8];
  }

  f32x16 aA0 = zero16(), aA1 = zero16(), aB0 = zero16(), aB1 = zero16();
  float mA = -INFINITY, lA = 0.f, mB = -INFINITY, lB = 0.f;

  for (int kt = 0; kt < kA; ++kt)
    tile_body<1, 1>(kh + (size_t)kt * 4096, vh + kt * 64, ql, hi,
                    qfA, aA0, aA1, mA, lA, qfB, aB0, aB1, mB, lB);
  if ((idx & 1) == 0)
    tile_body<2, 1>(kh + (size_t)kA * 4096, vh + kA * 64, ql, hi,
                    qfA, aA0, aA1, mA, lA, qfB, aB0, aB1, mB, lB);
  else
    tile_body<3, 1>(kh + (size_t)kA * 4096, vh + kA * 64, ql, hi,
                    qfA, aA0, aA1, mA, lA, qfB, aB0, aB1, mB, lB);
  for (int kt = kA + 1; kt < kB; ++kt)
    tile_body<0, 1>(kh + (size_t)kt * 4096, vh + kt * 64, ql, hi,
                    qfA, aA0, aA1, mA, lA, qfB, aB0, aB1, mB, lB);
  if ((idx & 1) == 0)
    tile_body<0, 3>(kh + (size_t)kB * 4096, vh + kB * 64, ql, hi,
                    qfA, aA0, aA1, mA, lA, qfB, aB0, aB1, mB, lB);
  else
    tile_body<0, 2>(kh + (size_t)kB * 4096, vh + kB * 64, ql, hi,
                    qfA, aA0, aA1, mA, lA, qfB, aB0, aB1, mB, lB);

  // pair-combine the half denominators (l kept per-lane inside the loop)
  lA += __shfl_xor(lA, 32);
  lB += __shfl_xor(lB, 32);
  const float invA = 1.f / lA, invB = 1.f / lB;
  unsigned short* orowA = O + (size_t)(b * S + 32 * gA + ql) * 1024 + h * 64;
  unsigned short* orowB = O + (size_t)(b * S + 32 * gB + ql) * 1024 + h * 64;
#pragma unroll
  for (int r = 0; r < 16; ++r) {
    int d = (r & 3) + 8 * (r >> 2) + 4 * hi;
    orowA[d] = f2bf(aA0[r] * invA);
    orowA[32 + d] = f2bf(aA1[r] * invA);
    orowB[d] = f2bf(aB0[r] * invB);
    orowB[32 + d] = f2bf(aB1[r] * invB);
  }
}

extern "C" void kernel_launch(void* const* d_in, const int* in_sizes, int n_in,
                              void* d_out, int out_size, void* d_ws, size_t ws_size,
                              hipStream_t stream) {
  const float* x = (const float*)d_in[0];
  const float* Wqkv = (const float*)d_in[1];
  const float* Wout = (const float*)d_in[2];
  float* out = (float*)d_out;

  char* ws = (char*)d_ws;
  size_t off = 0;
  auto take = [&](size_t bytes) {
    void* p = ws + off;
    off += (bytes + 255) & ~(size_t)255;
    return p;
  };
  float* tc = (float*)take(2048 * 32 * 4);
  float* tsn = (float*)take(2048 * 32 * 4);
  unsigned short* xbf = (unsigned short*)take((size_t)8192 * 1024 * 2);
  unsigned short* wqkvT = (unsigned short*)take((size_t)3072 * 1024 * 2);
  unsigned short* woutT = (unsigned short*)take((size_t)1024 * 1024 * 2);
  float* qkvf = (float*)take((size_t)8192 * 3072 * 4);
  unsigned short* qb_ = (unsigned short*)take((size_t)64 * 2048 * 64 * 2);
  unsigned short* kb_ = (unsigned short*)take((size_t)64 * 2048 * 64 * 2);
  unsigned short* vt = (unsigned short*)take((size_t)64 * 64 * 2048 * 2);
  unsigned short* attn = (unsigned short*)take((size_t)8192 * 1024 * 2);

  rope_table_kernel<<<256, 256, 0, stream>>>(tc, tsn);
  cvt_kernel<<<(2097152 + 255) / 256, 256, 0, stream>>>(x, xbf, 2097152);
  {
    dim3 g(96, 32);
    transpose_cvt<<<g, 256, 0, stream>>>(Wqkv, wqkvT, 1024, 3072);
  }
  {
    dim3 g(32, 32);
    transpose_cvt<<<g, 256, 0, stream>>>(Wout, woutT, 1024, 1024);
  }
  {
    dim3 g(24, 64);
    gemm_bt<<<g, 256, 0, stream>>>(xbf, wqkvT, qkvf, 8192, 3072, 1024);
  }
  rope_kernel<<<2048, 256, 0, stream>>>(qkvf, tc, tsn, qb_, kb_, vt);
  attn_kernel<<<512, 256, 0, stream>>>(qb_, kb_, vt, attn);
  {
    dim3 g(8, 64);
    gemm_bt<<<g, 256, 0, stream>>>(attn, woutT, out, 8192, 1024, 1024);
  }
}